// Round 1
// baseline (13679.247 us; speedup 1.0000x reference)
//
#include <hip/hip_runtime.h>

typedef _Float16 f16;
typedef f16  f16x8 __attribute__((ext_vector_type(8)));
typedef float f32x4 __attribute__((ext_vector_type(4)));
typedef unsigned long long u64;

// problem dims: B=128, T=256, E=H=512, L=4, 4H=2048
// ws layout (bytes)
#define OFF_XF  0ull          // fwd activation stream (T,B,512) f32  : 64 MB
#define OFF_XR  67108864ull   // rev (time-reversed) stream           : 64 MB
#define OFF_WP  134217728ull  // packed lstm weights f16 [L][2048][1024] (col-reordered+swizzled): 16 MB
#define OFF_WO  150994944ull  // out_W  f16 [512][1024]
#define OFF_WH  152043520ull  // hid_W  f16
#define OFF_WC  153092096ull  // cell_W f16
#define OFF_BC  154140672ull  // combined bias f32 [L][2048] (packed order)
#define OFF_HB  154173440ull  // h exchange buf f16 [dir][parity][128][512]
#define OFF_HT  154697728ull  // hT f32 [L][dir][128][512]
#define OFF_CT  156794880ull  // cT f32
#define OFF_CNT 158892032ull  // counters int [L][dir][half][256]

__device__ __forceinline__ float sigm(float x) { return 1.0f / (1.0f + expf(-x)); }

__device__ __forceinline__ f16x8 cvt8(const float* p) {
    float4 a0 = *(const float4*)p;
    float4 a1 = *(const float4*)(p + 4);
    f16x8 r;
    r[0]=(f16)a0.x; r[1]=(f16)a0.y; r[2]=(f16)a0.z; r[3]=(f16)a0.w;
    r[4]=(f16)a1.x; r[5]=(f16)a1.y; r[6]=(f16)a1.z; r[7]=(f16)a1.w;
    return r;
}

// ---------------- prep: pack weights fp16 (+LDS swizzle), combine biases, zero counters ----
__global__ __launch_bounds__(256) void prep_pack(
    const float* __restrict__ Wih, const float* __restrict__ Whh,
    const float* __restrict__ bih, const float* __restrict__ bhh,
    const float* __restrict__ oW, const float* __restrict__ hW, const float* __restrict__ cW,
    f16* __restrict__ Wp, f16* __restrict__ Wo, f16* __restrict__ Wh, f16* __restrict__ Wc,
    float* __restrict__ bc, int* __restrict__ cnt)
{
    const int blk = blockIdx.x, tid = threadIdx.x;
    if (blk < 8192) {
        // packed col p = cb*64 + gate*16 + j  ->  orig col = gate*512 + cb*16 + j
        const int l = blk >> 11, p = blk & 2047;
        const int cb = p >> 6, gate = (p >> 4) & 3, j = p & 15;
        const int orig = gate*512 + cb*16 + j;
        const int swz = (p & 7) << 3;                       // bank swizzle key (elements)
        const float* si = Wih + ((size_t)(l*2048 + orig) << 9);
        const float* sh = Whh + ((size_t)(l*2048 + orig) << 9);
        f16* d = Wp + ((size_t)(l*2048 + p) << 10);
        for (int k = tid; k < 1024; k += 256)
            d[k ^ swz] = (f16)((k < 512) ? si[k] : sh[k - 512]);
    } else if (blk < 9728) {
        const int which = (blk - 8192) >> 9;
        const int n = (blk - 8192) & 511;
        const float* s = which == 0 ? oW : (which == 1 ? hW : cW);
        f16* d = which == 0 ? Wo : (which == 1 ? Wh : Wc);
        for (int k = tid; k < 1024; k += 256)
            d[((size_t)n << 10) + k] = (f16)s[((size_t)n << 10) + k];
    } else if (blk == 9728) {
        for (int i = tid; i < 8192; i += 256) {
            const int l = i >> 11, p = i & 2047;
            const int cb = p >> 6, gate = (p >> 4) & 3, j = p & 15;
            const int orig = l*2048 + gate*512 + cb*16 + j;
            bc[i] = bih[orig] + bhh[orig];
        }
    } else {
        for (int i = tid; i < 4096; i += 256) cnt[i] = 0;
    }
}

// ---------------- embedding + relu, writes fwd and time-reversed streams -------------------
__global__ __launch_bounds__(256) void embed_relu(
    const int* __restrict__ ids, const float* __restrict__ emb,
    float* __restrict__ Xf, float* __restrict__ Xr)
{
    const int blk = blockIdx.x;               // 0..32767
    const int b = blk >> 8, t = blk & 255;
    const int id = ids[b*256 + t];
    float2 v = *((const float2*)(emb + ((size_t)id << 9)) + threadIdx.x);
    v.x = fmaxf(v.x, 0.f); v.y = fmaxf(v.y, 0.f);
    const size_t e2 = (size_t)threadIdx.x * 2;
    *(float2*)(Xf + (((size_t)t*128 + b) << 9) + e2) = v;
    *(float2*)(Xr + (((size_t)(255 - t)*128 + b) << 9) + e2) = v;
}

// ---------------- persistent per-layer LSTM (both directions), flag-synced -----------------
// grid 128 = dir(2) x half(2) x cb(32).  Block owns 16 hidden cols (64 gate cols), W in LDS.
__global__ __launch_bounds__(256, 1) void lstm_layer(
    const int l,
    const f16* __restrict__ Wp, const float* __restrict__ bc,
    float* __restrict__ Xf, float* __restrict__ Xr,
    f16* __restrict__ hbuf, float* __restrict__ hT, float* __restrict__ cT,
    int* __restrict__ cnt)
{
    extern __shared__ char smem[];
    f16*   Wlds  = (f16*)smem;                        // 64 x 1024 f16 = 128 KB
    float* Gs    = (float*)(smem + 131072);           // 64 x 65 f32 (padded)
    float* biasS = (float*)(smem + 131072 + 16640);   // 64

    const int tid  = threadIdx.x;
    const int blk  = blockIdx.x;
    const int dir  = blk >> 6;
    const int half = (blk >> 5) & 1;
    const int cb   = blk & 31;
    const int w    = tid >> 6;
    const int ln15 = tid & 15;
    const int kgrp = ((tid & 63) >> 4) << 3;

    {   // stage weight slice (swizzle already baked into global layout)
        const float4* src = (const float4*)(Wp + ((size_t)(l*2048 + cb*64) << 10));
        float4* dst = (float4*)Wlds;
        for (int i = tid; i < 8192; i += 256) dst[i] = src[i];
        if (tid < 64) biasS[tid] = bc[l*2048 + cb*64 + tid];
    }
    __syncthreads();

    float* X = dir ? Xr : Xf;
    f16* hb = hbuf + (size_t)dir * 131072;
    int* cp = cnt + (((l*2 + dir)*2 + half) << 8);

    const int arow = half*64 + w*16 + ln15;           // A row (batch index)
    const int swz  = (ln15 & 7) << 3;

    const int erow = tid >> 2;                        // elementwise: 64 rows x 4 threads
    const int eb   = half*64 + erow;
    const int ecl  = (tid & 3) << 2;                  // local col base (0,4,8,12)
    const int ecol = cb*16 + ecl;                     // global hidden col base

    float creg[4] = {0.f, 0.f, 0.f, 0.f};
    float4 xdef = {0.f, 0.f, 0.f, 0.f};

    for (int t = 0; t < 256; ++t) {
        if (t > 0) {
            if (tid == 0) {                           // wait for whole (dir,half) group @ t-1
                int g = 0;
                while (__hip_atomic_load(cp + (t - 1), __ATOMIC_ACQUIRE, __HIP_MEMORY_SCOPE_AGENT) < 32) {
                    __builtin_amdgcn_s_sleep(1);
                    if (++g > 32768) break;           // deadlock bail (turns hang into bad absmax)
                }
            }
            __syncthreads();
            // deferred residual update of X[t-1] (safe: all group reads of X[t-1] are done)
            *(float4*)(X + ((size_t)(t - 1) << 16) + ((size_t)eb << 9) + ecol) = xdef;
        }

        f32x4 acc[4] = {{0,0,0,0},{0,0,0,0},{0,0,0,0},{0,0,0,0}};
        const float* xrow = X + ((size_t)t << 16) + ((size_t)arow << 9);

        #pragma unroll 4
        for (int ks = 0; ks < 16; ++ks) {             // input half of K (X[t], fp32->fp16)
            const int ko = (ks << 5) + kgrp;
            const f16x8 af = cvt8(xrow + ko);
            #pragma unroll
            for (int ct = 0; ct < 4; ++ct) {
                const f16x8 bf = *(const f16x8*)(Wlds + ((ct*16 + ln15) << 10) + (ko ^ swz));
                acc[ct] = __builtin_amdgcn_mfma_f32_16x16x32_f16(af, bf, acc[ct], 0, 0, 0);
            }
        }
        if (t > 0) {                                  // recurrent half of K (h[t-1], sc1 loads)
            const f16* hrow = hb + ((size_t)((t & 1) ^ 1) << 16) + ((size_t)arow << 9);
            #pragma unroll 4
            for (int ks = 0; ks < 16; ++ks) {
                const int koh = (ks << 5) + kgrp;
                u64* hp = (u64*)(hrow + koh);
                union { u64 q[2]; f16x8 v; } uu;
                uu.q[0] = __hip_atomic_load(hp,     __ATOMIC_RELAXED, __HIP_MEMORY_SCOPE_AGENT);
                uu.q[1] = __hip_atomic_load(hp + 1, __ATOMIC_RELAXED, __HIP_MEMORY_SCOPE_AGENT);
                const int ko = 512 + koh;
                #pragma unroll
                for (int ct = 0; ct < 4; ++ct) {
                    const f16x8 bf = *(const f16x8*)(Wlds + ((ct*16 + ln15) << 10) + (ko ^ swz));
                    acc[ct] = __builtin_amdgcn_mfma_f32_16x16x32_f16(uu.v, bf, acc[ct], 0, 0, 0);
                }
            }
        }

        // gates -> LDS (padded to kill bank conflicts on the transposed read)
        const int grow = w*16 + (((tid & 63) >> 4) << 2);
        #pragma unroll
        for (int ct = 0; ct < 4; ++ct)
            #pragma unroll
            for (int r = 0; r < 4; ++r)
                Gs[(grow + r)*65 + ct*16 + ln15] = acc[ct][r];
        __syncthreads();

        float hq[4];
        #pragma unroll
        for (int j2 = 0; j2 < 4; ++j2) {
            const int col = ecl + j2;
            const float gi = Gs[erow*65 + col     ] + biasS[col];
            const float gf = Gs[erow*65 + col + 16] + biasS[col + 16];
            const float gg = Gs[erow*65 + col + 32] + biasS[col + 32];
            const float go = Gs[erow*65 + col + 48] + biasS[col + 48];
            const float cn = sigm(gf)*creg[j2] + sigm(gi)*tanhf(gg);
            const float hv = sigm(go)*tanhf(cn);
            creg[j2] = cn;
            hq[j2] = hv;
        }
        const float4 xold = *(const float4*)(X + ((size_t)t << 16) + ((size_t)eb << 9) + ecol);
        xdef.x = xold.x + hq[0];
        xdef.y = xold.y + hq[1];
        xdef.z = xold.z + hq[2];
        xdef.w = xold.w + hq[3];

        union { u64 q; f16 h4[4]; } hu;
        hu.h4[0]=(f16)hq[0]; hu.h4[1]=(f16)hq[1]; hu.h4[2]=(f16)hq[2]; hu.h4[3]=(f16)hq[3];
        __hip_atomic_store((u64*)(hb + ((size_t)(t & 1) << 16) + ((size_t)eb << 9) + ecol), hu.q,
                           __ATOMIC_RELAXED, __HIP_MEMORY_SCOPE_AGENT);
        if (t == 255) {
            const size_t o = (((size_t)(l*2 + dir)*128 + eb) << 9) + ecol;
            #pragma unroll
            for (int j2 = 0; j2 < 4; ++j2) { hT[o + j2] = hq[j2]; cT[o + j2] = creg[j2]; }
        }
        __syncthreads();   // drains vmcnt: all h stores of this block complete (at IC, sc1)
        if (tid == 0)
            __hip_atomic_fetch_add(cp + t, 1, __ATOMIC_RELEASE, __HIP_MEMORY_SCOPE_AGENT);
    }

    // flush the final deferred residual write (after everyone has read X[255])
    if (tid == 0) {
        int g = 0;
        while (__hip_atomic_load(cp + 255, __ATOMIC_ACQUIRE, __HIP_MEMORY_SCOPE_AGENT) < 32) {
            __builtin_amdgcn_s_sleep(1);
            if (++g > 32768) break;
        }
    }
    __syncthreads();
    *(float4*)(X + ((size_t)255 << 16) + ((size_t)eb << 9) + ecol) = xdef;
}

// ---------------- out = concat(fo, ro) @ out_W^T + out_b  (M=32768, N=512, K=1024) ---------
__global__ __launch_bounds__(256) void proj_out(
    const float* __restrict__ Xf, const float* __restrict__ Xr,
    const f16* __restrict__ Wo, const float* __restrict__ ob,
    float* __restrict__ out)
{
    const int blk = blockIdx.x;
    const int mb = (blk >> 3) << 6;
    const int nb = (blk & 7) << 6;
    const int w = threadIdx.x >> 6, ln15 = threadIdx.x & 15;
    const int kgrp = ((threadIdx.x & 63) >> 4) << 3;
    const int m = mb + w*16 + ln15;              // m = b*256 + t
    const int t = m & 255, b = m >> 8;
    const float* af_ = Xf + (((size_t)t*128 + b) << 9);
    const float* ar_ = Xr + (((size_t)(255 - t)*128 + b) << 9);  // ro = reversed rev stream
    f32x4 acc[4] = {{0,0,0,0},{0,0,0,0},{0,0,0,0},{0,0,0,0}};
    #pragma unroll 2
    for (int ks = 0; ks < 32; ++ks) {
        const int ko = (ks << 5) + kgrp;
        const f16x8 af = cvt8(ks < 16 ? af_ + ko : ar_ + (ko - 512));
        #pragma unroll
        for (int ct = 0; ct < 4; ++ct) {
            const int n = nb + ct*16 + ln15;
            const f16x8 bf = *(const f16x8*)(Wo + ((size_t)n << 10) + ko);
            acc[ct] = __builtin_amdgcn_mfma_f32_16x16x32_f16(af, bf, acc[ct], 0, 0, 0);
        }
    }
    const int r0 = mb + w*16 + (((threadIdx.x & 63) >> 4) << 2);
    #pragma unroll
    for (int ct = 0; ct < 4; ++ct) {
        const int n = nb + ct*16 + ln15;
        const float bb = ob[n];
        #pragma unroll
        for (int r = 0; r < 4; ++r)
            out[((size_t)(r0 + r) << 9) + n] = acc[ct][r] + bb;
    }
}

// ---------------- hidden/cell projections (M=512, N=512, K=1024) ---------------------------
__global__ __launch_bounds__(256) void proj_state(
    const float* __restrict__ hT, const float* __restrict__ cT,
    const f16* __restrict__ Wh, const f16* __restrict__ Wc,
    const float* __restrict__ hb_, const float* __restrict__ cb_,
    float* __restrict__ out)
{
    const int blk = blockIdx.x;
    const int z = blk >> 6;                       // 0 hidden, 1 cell
    const int sub = blk & 63;
    const int mb = (sub >> 3) << 6;
    const int nb = (sub & 7) << 6;
    const int w = threadIdx.x >> 6, ln15 = threadIdx.x & 15;
    const int kgrp = ((threadIdx.x & 63) >> 4) << 3;
    const int m = mb + w*16 + ln15;               // m = l*128 + b
    const int l = m >> 7, b = m & 127;
    const float* A = z ? cT : hT;
    const f16*  W  = z ? Wc : Wh;
    const float* bi = z ? cb_ : hb_;
    const float* a0 = A + (((size_t)(l*2 + 0)*128 + b) << 9);
    const float* a1 = A + (((size_t)(l*2 + 1)*128 + b) << 9);
    f32x4 acc[4] = {{0,0,0,0},{0,0,0,0},{0,0,0,0},{0,0,0,0}};
    for (int ks = 0; ks < 32; ++ks) {
        const int ko = (ks << 5) + kgrp;
        const f16x8 af = cvt8(ks < 16 ? a0 + ko : a1 + (ko - 512));
        #pragma unroll
        for (int ct = 0; ct < 4; ++ct) {
            const int n = nb + ct*16 + ln15;
            const f16x8 bf = *(const f16x8*)(W + ((size_t)n << 10) + ko);
            acc[ct] = __builtin_amdgcn_mfma_f32_16x16x32_f16(af, bf, acc[ct], 0, 0, 0);
        }
    }
    float* o = out + (size_t)z * 262144;
    const int r0 = mb + w*16 + (((threadIdx.x & 63) >> 4) << 2);
    #pragma unroll
    for (int ct = 0; ct < 4; ++ct) {
        const int n = nb + ct*16 + ln15;
        const float bb = bi[n];
        #pragma unroll
        for (int r = 0; r < 4; ++r)
            o[((size_t)(r0 + r) << 9) + n] = acc[ct][r] + bb;
    }
}

extern "C" void kernel_launch(void* const* d_in, const int* in_sizes, int n_in,
                              void* d_out, int out_size, void* d_ws, size_t ws_size,
                              hipStream_t stream)
{
    const int*   enc  = (const int*)d_in[0];
    const float* emb  = (const float*)d_in[1];
    const float* Wih  = (const float*)d_in[2];
    const float* Whh  = (const float*)d_in[3];
    const float* bih  = (const float*)d_in[4];
    const float* bhh  = (const float*)d_in[5];
    const float* oW   = (const float*)d_in[6];
    const float* obv  = (const float*)d_in[7];
    const float* hW   = (const float*)d_in[8];
    const float* hbv  = (const float*)d_in[9];
    const float* cW   = (const float*)d_in[10];
    const float* cbv  = (const float*)d_in[11];
    float* out = (float*)d_out;
    char* ws = (char*)d_ws;

    float* Xf = (float*)(ws + OFF_XF);
    float* Xr = (float*)(ws + OFF_XR);
    f16* Wp   = (f16*)(ws + OFF_WP);
    f16* Wo   = (f16*)(ws + OFF_WO);
    f16* Wh   = (f16*)(ws + OFF_WH);
    f16* Wc   = (f16*)(ws + OFF_WC);
    float* bc = (float*)(ws + OFF_BC);
    f16* hb   = (f16*)(ws + OFF_HB);
    float* hT = (float*)(ws + OFF_HT);
    float* cT = (float*)(ws + OFF_CT);
    int* cnt  = (int*)(ws + OFF_CNT);

    hipFuncSetAttribute((const void*)lstm_layer,
                        hipFuncAttributeMaxDynamicSharedMemorySize, 147968);

    prep_pack<<<9730, 256, 0, stream>>>(Wih, Whh, bih, bhh, oW, hW, cW,
                                        Wp, Wo, Wh, Wc, bc, cnt);
    embed_relu<<<32768, 256, 0, stream>>>(enc, emb, Xf, Xr);
    for (int l = 0; l < 4; ++l)
        lstm_layer<<<128, 256, 147968, stream>>>(l, Wp, bc, Xf, Xr, hb, hT, cT, cnt);
    proj_out<<<4096, 256, 0, stream>>>(Xf, Xr, Wo, obv, out);
    proj_state<<<128, 256, 0, stream>>>(hT, cT, Wh, Wc, hbv, cbv, out + 16777216);
}